// Round 4
// baseline (138.359 us; speedup 1.0000x reference)
//
#include <hip/hip_runtime.h>
#include <stdint.h>

#define NCLS   80
#define HWTOT  21824
#define MBOX   100
#define ROWS   349184        // 16*21824

// flat f32 output layout (return-order concat)
#define REG_OFF 28633088ull   // 16*21824*82
#define IND_OFF 30728192ull   // + 16*21824*6
#define NB_OFF  31077376ull   // + 16*21824

#define N4C 7158272   // cls region float4 count (ROWS*82/4)
#define N4R 523776    // reg region float4 count (ROWS*6/4)

// ===================== kernel A: per-row target meta =====================
__global__ __launch_bounds__(256)
void sapd_meta(const float* __restrict__ gt, float* __restrict__ out,
               float4* __restrict__ m0, float4* __restrict__ m1)
{
    const int tid = threadIdx.x;
    const int c   = blockIdx.x;   // chunk id within batch, 0..85
    const int b   = blockIdx.y;   // batch 0..15

    int lvl, pix0, base;
    if      (c < 64) { lvl = 0; pix0 = c << 8;        base = 0;     }
    else if (c < 80) { lvl = 1; pix0 = (c - 64) << 8; base = 16384; }
    else if (c < 84) { lvl = 2; pix0 = (c - 80) << 8; base = 20480; }
    else if (c < 85) { lvl = 3; pix0 = 0;             base = 21504; }
    else             { lvl = 4; pix0 = 0;             base = 21760; }

    const int   l2fw   = 7 - lvl;        // fw: 128,64,32,16,8
    const int   fw     = 1 << l2fw;
    const float fs     = (float)(8 << lvl);
    const int   chunkN = (lvl == 4) ? 64 : 256;

    const size_t rowbase = (size_t)b * HWTOT + base + pix0;

    __shared__ uint32_t sBB[MBOX];
    __shared__ float    sArea[MBOX];
    __shared__ int      sValid[MBOX];
    __shared__ float4   sBox[MBOX];
    __shared__ int      sLab[MBOX];
    __shared__ float2   sCull[MBOX];
    __shared__ int      sOrig[MBOX];
    __shared__ int      sN;

    // phase 1: per-box precompute
    if (tid < MBOX) {
        const float* g = gt + ((size_t)b * MBOX + tid) * 5;
        float x1 = g[0], y1 = g[1], x2 = g[2], y2 = g[3], lab = g[4];
        int valid = (fabsf(x1) + fabsf(y1) + fabsf(x2) + fabsf(y2)) > 0.0f;
        float area = (x2 - x1) * (y2 - y1);
        float bx1 = x1 / fs, by1 = y1 / fs, bx2 = x2 / fs, by2 = y2 / fs;
        float cx = (bx1 + bx2) * 0.5f, cy = (by1 + by2) * 0.5f;
        float hw = (bx2 - bx1) * 0.5f * 0.2f, hh = (by2 - by1) * 0.5f * 0.2f;
        float px1 = fmaxf(floorf(cx - hw), 0.0f);
        float py1 = fmaxf(floorf(cy - hh), 0.0f);
        float px2 = fminf(ceilf(cx + hw), (float)fw);
        float py2 = fminf(ceilf(cy + hh), (float)fw);
        uint32_t bb = (uint32_t)px1 | ((uint32_t)py1 << 8) |
                      ((uint32_t)px2 << 16) | ((uint32_t)py2 << 24);
        sBB[tid]    = bb;
        sArea[tid]  = area;
        sValid[tid] = valid;
        sBox[tid]   = make_float4(x1, y1, x2, y2);
        sLab[tid]   = (int)lab;
    }
    __syncthreads();

    if (lvl == 4 && tid == 64) {
        int cnt = 0;
        for (int m = 0; m < MBOX; ++m) cnt += sValid[m];
        out[NB_OFF + b] = (float)cnt;
    }

    // phase 2: wave-0 order-preserving row-band cull
    if (tid < 64) {
        const int lane = tid;
        const int ry0 = pix0 >> l2fw;
        const int ry1 = ry0 + (chunkN >> l2fw);
        int n0;
        {
            int m = lane;
            uint32_t bb = sBB[m];
            int ix1 = bb & 255, iy1 = (bb >> 8) & 255, ix2 = (bb >> 16) & 255, iy2 = bb >> 24;
            bool pred = sValid[m] && (ix2 > ix1) && (iy2 > ry0) && (iy1 < ry1);
            unsigned long long mk = __ballot(pred);
            n0 = __popcll(mk);
            if (pred) {
                int p = __popcll(mk & ((1ull << lane) - 1ull));
                sCull[p] = make_float2(__uint_as_float(bb), sArea[m]);
                sOrig[p] = m;
            }
        }
        {
            int m = 64 + lane;
            bool pred = false;
            uint32_t bb = 0;
            float ar = 0.0f;
            if (m < MBOX) {
                bb = sBB[m]; ar = sArea[m];
                int ix1 = bb & 255, iy1 = (bb >> 8) & 255, ix2 = (bb >> 16) & 255, iy2 = bb >> 24;
                pred = sValid[m] && (ix2 > ix1) && (iy2 > ry0) && (iy1 < ry1);
            }
            unsigned long long mk = __ballot(pred);
            if (pred) {
                int p = n0 + __popcll(mk & ((1ull << lane) - 1ull));
                sCull[p] = make_float2(__uint_as_float(bb), ar);
                sOrig[p] = m;
            }
            if (lane == 0) sN = n0 + __popcll(mk);
        }
    }
    __syncthreads();

    // phase 3: per-pixel argmin + target math -> global row meta
    if (tid < chunkN) {
        const int p  = pix0 + tid;
        const int px = p & (fw - 1);
        const int py = p >> l2fw;
        float bestA = 1e30f; int bestI = -1;
        const int n = sN;
        for (int i = 0; i < n; ++i) {
            float2 e = sCull[i];
            uint32_t bb = __float_as_uint(e.x);
            int x1 = bb & 255, y1 = (bb >> 8) & 255, x2 = (bb >> 16) & 255, y2 = bb >> 24;
            bool hit = (px >= x1) & (px < x2) & (py >= y1) & (py < y2);
            bool upd = hit & (e.y < bestA);   // strict < keeps first on ties
            bestA = upd ? e.y : bestA;
            bestI = upd ? i : bestI;
        }
        bool pos = bestI >= 0;
        int orig = pos ? sOrig[bestI] : 0;
        float4 bx = sBox[orig];
        float sx = ((float)px + 0.5f) * fs;
        float sy = ((float)py + 0.5f) * fs;
        float l  = sx - bx.x, t = sy - bx.y, r = bx.z - sx, bt = bx.w - sy;
        float inv4s = 1.0f / (4.0f * fs);   // power of two: exact vs reference divide
        float posf  = pos ? 1.0f : 0.0f;
        const float eps = 1e-6f;
        float a1 = fminf(l, r) / fmaxf(fmaxf(l, r), eps);
        a1 = fminf(fmaxf(a1, 0.0f), 1.0f);
        float a2 = fminf(t, bt) / fmaxf(fmaxf(t, bt), eps);
        a2 = fminf(fmaxf(a2, 0.0f), 1.0f);
        float cent = sqrtf(a1 * a2);
        float soft = pos ? cent : 1.0f;
        int   tgt  = pos ? sLab[orig] : 0x7fffffff;  // never matches a col when !pos
        const size_t grow = rowbase + tid;
        m0[grow] = make_float4(soft, posf, __int_as_float(tgt), 0.0f);
        m1[grow] = make_float4(l * inv4s * posf, t * inv4s * posf,
                               r * inv4s * posf, bt * inv4s * posf);
        out[IND_OFF + grow] = pos ? (float)orig : -1.0f;
    }
}

// ===================== kernel B: barrier-free expansion stream =====================
__global__ __launch_bounds__(256)
void sapd_expand(const float4* __restrict__ m0, const float4* __restrict__ m1,
                 float* __restrict__ out)
{
    const int gtid   = blockIdx.x * 256 + threadIdx.x;
    const int stride = gridDim.x * 256;

    // ---- cls region: ROWS x 82, each float4 written exactly once ----
    // col0 = 4i mod 82 is even; float4 straddles rows iff col0 == 80.
    float4* oc = (float4*)out;
    for (int i = gtid; i < N4C; i += stride) {
        const int id   = i << 2;
        const unsigned row = (unsigned)id / 82u;       // magic-mul
        const int col0 = id - (int)row * 82;
        const bool wrap = (col0 == 80);
        float4 ma = m0[row];
        float4 mb = m0[row + (wrap ? 1 : 0)];          // address-select: no OOB at last row
        const int tgt1 = __float_as_int(ma.z);
        float v0 = (col0 < 80) ? ((col0 == tgt1) ? 1.0f : 0.0f) : ma.x;  // 80 -> soft
        const int c1 = col0 + 1;                                          // odd, never 80
        float v1 = (c1 < 80) ? ((c1 == tgt1) ? 1.0f : 0.0f) : ma.y;       // 81 -> posf
        const int tgt2 = __float_as_int(mb.z);
        const int c2 = wrap ? 0 : col0 + 2;
        const int c3 = wrap ? 1 : col0 + 3;
        float v2 = (c2 < 80) ? ((c2 == tgt2) ? 1.0f : 0.0f)
                             : ((c2 == 80) ? mb.x : mb.y);
        float v3 = (c3 < 80) ? ((c3 == tgt2) ? 1.0f : 0.0f)
                             : ((c3 == 80) ? mb.x : mb.y);
        oc[i] = make_float4(v0, v1, v2, v3);
    }

    // ---- reg region: ROWS x 6 ----
    // col0 = 4i mod 6 ∈ {0,2,4}; straddles rows iff col0 == 4.
    float4* orr = (float4*)(out + REG_OFF);
    for (int i = gtid; i < N4R; i += stride) {
        const int id   = i << 2;
        const unsigned row = (unsigned)id / 6u;
        const int col0 = id - (int)row * 6;
        const bool w4 = (col0 == 4);
        float4 a  = m0[row];
        float4 rg = m1[row];
        float4 r2 = m1[row + (w4 ? 1 : 0)];
        float4 v;
        if (col0 == 0)      v = rg;                                  // l,t,r,b
        else if (col0 == 2) v = make_float4(rg.z, rg.w, a.x, a.y);   // r,b,soft,posf
        else                v = make_float4(a.x, a.y, r2.x, r2.y);   // soft,posf,l',t'
        orr[i] = v;
    }
}

extern "C" void kernel_launch(void* const* d_in, const int* in_sizes, int n_in,
                              void* d_out, int out_size, void* d_ws, size_t ws_size,
                              hipStream_t stream)
{
    const float* gt = (const float*)d_in[0];
    float* out = (float*)d_out;
    float4* m0 = (float4*)d_ws;              // ROWS x {soft,posf,tgt,0}
    float4* m1 = m0 + ROWS;                  // ROWS x {l,t,r,b}
    sapd_meta<<<dim3(86, 16), 256, 0, stream>>>(gt, out, m0, m1);
    sapd_expand<<<2048, 256, 0, stream>>>(m0, m1, out);
}

// Round 5
// 126.139 us; speedup vs baseline: 1.0969x; 1.0969x over previous
//
#include <hip/hip_runtime.h>
#include <stdint.h>

#define NCLS   80
#define HWTOT  21824
#define MBOX   100

// flat f32 output layout (return-order concat)
#define REG_OFF 28633088ull   // 16*21824*82
#define IND_OFF 30728192ull   // + 16*21824*6
#define NB_OFF  31077376ull   // + 16*21824

__global__ __launch_bounds__(256)
void sapd_targets(const float* __restrict__ gt, float* __restrict__ out)
{
    const int tid = threadIdx.x;
    const int c   = blockIdx.x;   // chunk id within batch, 0..85
    const int b   = blockIdx.y;   // batch 0..15

    // chunk -> (level, pixel0, level base). Chunks never cross level bounds.
    int lvl, pix0, base;
    if      (c < 64) { lvl = 0; pix0 = c << 8;        base = 0;     }
    else if (c < 80) { lvl = 1; pix0 = (c - 64) << 8; base = 16384; }
    else if (c < 84) { lvl = 2; pix0 = (c - 80) << 8; base = 20480; }
    else if (c < 85) { lvl = 3; pix0 = 0;             base = 21504; }
    else             { lvl = 4; pix0 = 0;             base = 21760; }

    const int   l2fw   = 7 - lvl;        // fw: 128,64,32,16,8
    const int   fw     = 1 << l2fw;
    const float fs     = (float)(8 << lvl);
    const int   chunkN = (lvl == 4) ? 64 : 256;

    const size_t rowbase = (size_t)b * HWTOT + base + pix0;  // always even

    __shared__ uint32_t sBB[MBOX];     // packed shrunk bounds (u8 x4)
    __shared__ float    sArea[MBOX];
    __shared__ int      sValid[MBOX];
    __shared__ float4   sBox[MBOX];    // original image-space coords
    __shared__ int      sLab[MBOX];
    __shared__ float2   sCull[MBOX];   // {bounds as float bits, area}
    __shared__ int      sOrig[MBOX];
    __shared__ int      sN;
    __shared__ float4   sMeta[257];    // {soft, posf, tgt_as_bits, 0} per row
    __shared__ float    rReg[256 * 4];

    // ---- phase 1: per-box precompute. gt load is the FIRST memory op ----
    if (tid < MBOX) {
        const float* g = gt + ((size_t)b * MBOX + tid) * 5;
        float x1 = g[0], y1 = g[1], x2 = g[2], y2 = g[3], lab = g[4];
        int valid = (fabsf(x1) + fabsf(y1) + fabsf(x2) + fabsf(y2)) > 0.0f;
        float area = (x2 - x1) * (y2 - y1);
        float bx1 = x1 / fs, by1 = y1 / fs, bx2 = x2 / fs, by2 = y2 / fs;
        float cx = (bx1 + bx2) * 0.5f, cy = (by1 + by2) * 0.5f;
        float hw = (bx2 - bx1) * 0.5f * 0.2f, hh = (by2 - by1) * 0.5f * 0.2f;
        float px1 = fmaxf(floorf(cx - hw), 0.0f);
        float py1 = fmaxf(floorf(cy - hh), 0.0f);
        float px2 = fminf(ceilf(cx + hw), (float)fw);
        float py2 = fminf(ceilf(cy + hh), (float)fw);
        uint32_t bb = (uint32_t)px1 | ((uint32_t)py1 << 8) |
                      ((uint32_t)px2 << 16) | ((uint32_t)py2 << 24);
        sBB[tid]    = bb;
        sArea[tid]  = area;
        sValid[tid] = valid;
        sBox[tid]   = make_float4(x1, y1, x2, y2);
        sLab[tid]   = (int)lab;
    }
    __syncthreads();

    // num_boxes: lvl-4 blocks (one per batch), thread 64 idle in phase 3
    if (lvl == 4 && tid == 64) {
        int cnt = 0;
        for (int m = 0; m < MBOX; ++m) cnt += sValid[m];
        out[NB_OFF + b] = (float)cnt;
    }

    // ---- phase 2: wave-0 order-preserving row-band cull ----
    if (tid < 64) {
        const int lane = tid;
        const int ry0 = pix0 >> l2fw;
        const int ry1 = ry0 + (chunkN >> l2fw);
        int n0;
        {
            int m = lane;   // m < 64 < MBOX always
            uint32_t bb = sBB[m];
            int ix1 = bb & 255, iy1 = (bb >> 8) & 255, ix2 = (bb >> 16) & 255, iy2 = bb >> 24;
            bool pred = sValid[m] && (ix2 > ix1) && (iy2 > ry0) && (iy1 < ry1);
            unsigned long long mk = __ballot(pred);
            n0 = __popcll(mk);
            if (pred) {
                int p = __popcll(mk & ((1ull << lane) - 1ull));
                sCull[p] = make_float2(__uint_as_float(bb), sArea[m]);
                sOrig[p] = m;
            }
        }
        {
            int m = 64 + lane;
            bool pred = false;
            uint32_t bb = 0;
            float ar = 0.0f;
            if (m < MBOX) {
                bb = sBB[m]; ar = sArea[m];
                int ix1 = bb & 255, iy1 = (bb >> 8) & 255, ix2 = (bb >> 16) & 255, iy2 = bb >> 24;
                pred = sValid[m] && (ix2 > ix1) && (iy2 > ry0) && (iy1 < ry1);
            }
            unsigned long long mk = __ballot(pred);
            if (pred) {
                int p = n0 + __popcll(mk & ((1ull << lane) - 1ull));
                sCull[p] = make_float2(__uint_as_float(bb), ar);
                sOrig[p] = m;
            }
            if (lane == 0) sN = n0 + __popcll(mk);
        }
    }
    __syncthreads();

    // ---- phase 3: per-pixel argmin + target math -> packed row meta in LDS ----
    if (tid < chunkN) {
        const int p  = pix0 + tid;
        const int px = p & (fw - 1);
        const int py = p >> l2fw;
        float bestA = 1e30f; int bestI = -1;
        const int n = sN;
        for (int i = 0; i < n; ++i) {
            float2 e = sCull[i];
            uint32_t bb = __float_as_uint(e.x);
            int x1 = bb & 255, y1 = (bb >> 8) & 255, x2 = (bb >> 16) & 255, y2 = bb >> 24;
            bool hit = (px >= x1) & (px < x2) & (py >= y1) & (py < y2);
            bool upd = hit & (e.y < bestA);   // strict < keeps first (orig-order) on ties
            bestA = upd ? e.y : bestA;
            bestI = upd ? i : bestI;
        }
        bool pos = bestI >= 0;
        int orig = pos ? sOrig[bestI] : 0;
        float4 bx = sBox[orig];
        float sx = ((float)px + 0.5f) * fs;
        float sy = ((float)py + 0.5f) * fs;
        float l  = sx - bx.x, t = sy - bx.y, r = bx.z - sx, bt = bx.w - sy;
        float inv4s = 1.0f / (4.0f * fs);   // power of two: exact vs reference divide
        float posf  = pos ? 1.0f : 0.0f;
        const float eps = 1e-6f;
        float a1 = fminf(l, r) / fmaxf(fmaxf(l, r), eps);
        a1 = fminf(fmaxf(a1, 0.0f), 1.0f);
        float a2 = fminf(t, bt) / fmaxf(fmaxf(t, bt), eps);
        a2 = fminf(fmaxf(a2, 0.0f), 1.0f);
        float cent = sqrtf(a1 * a2);
        float soft = pos ? cent : 1.0f;
        int   tgt  = pos ? sLab[orig] : 0x7fffffff;  // never matches a col when !pos
        sMeta[tid] = make_float4(soft, posf, __int_as_float(tgt), 0.0f);
        rReg[tid * 4 + 0] = l  * inv4s * posf;
        rReg[tid * 4 + 1] = t  * inv4s * posf;
        rReg[tid * 4 + 2] = r  * inv4s * posf;
        rReg[tid * 4 + 3] = bt * inv4s * posf;
        out[IND_OFF + rowbase + tid] = pos ? (float)orig : -1.0f;
    }
    __syncthreads();

    // ---- phase 4: single-pass streaming stores (each dword written once) ----
    // cls region: chunkN rows x 82 cols, flat float4 loop.
    // col0 = 4i mod 82 is always even -> a float4 straddles rows iff col0 == 80,
    // and (82*chunkN) % 4 == 0 means no float4 crosses the block boundary.
    {
        float4* o4 = (float4*)(out + rowbase * 82);   // rowbase even -> 16B aligned
        const int n4 = (chunkN * 82) >> 2;            // 5248 or 1312
        for (int i = tid; i < n4; i += 256) {
            const int id   = i << 2;
            const unsigned row = (unsigned)id / 82u;  // magic-mul
            const int col0 = id - (int)row * 82;
            float4 m1 = sMeta[row];
            float4 m2 = sMeta[row + 1];
            const bool wrap = (col0 == 80);
            const int tgt1 = __float_as_int(m1.z);
            float v0 = (col0 < 80) ? ((col0 == tgt1) ? 1.0f : 0.0f) : m1.x; // col0==80 -> soft
            const int c1 = col0 + 1;                                        // odd, never 80
            float v1 = (c1 < 80) ? ((c1 == tgt1) ? 1.0f : 0.0f) : m1.y;     // c1==81 -> posf
            float soft2 = wrap ? m2.x : m1.x;
            float posf2 = wrap ? m2.y : m1.y;
            int   tgt2  = __float_as_int(wrap ? m2.z : m1.z);
            const int c2 = wrap ? 0 : col0 + 2;
            const int c3 = wrap ? 1 : col0 + 3;
            float v2 = (c2 < 80) ? ((c2 == tgt2) ? 1.0f : 0.0f)
                                 : ((c2 == 80) ? soft2 : posf2);
            float v3 = (c3 < 80) ? ((c3 == tgt2) ? 1.0f : 0.0f)
                                 : ((c3 == 80) ? soft2 : posf2);
            o4[i] = make_float4(v0, v1, v2, v3);
        }
    }

    // reg region: contiguous float4 fill from LDS
    {
        float4* o4 = (float4*)(out + REG_OFF + rowbase * 6);   // 16B-aligned
        const int n4 = (chunkN * 6) >> 2;   // 384 or 96
        for (int i = tid; i < n4; i += 256) {
            int idx = i << 2;
            float v[4];
            #pragma unroll
            for (int k = 0; k < 4; ++k) {
                int id  = idx + k;
                int row = (int)((unsigned)id / 6u);
                int col = id - row * 6;
                float4 m = sMeta[row];
                v[k] = (col < 4) ? rReg[row * 4 + col] : ((col == 4) ? m.x : m.y);
            }
            o4[i] = make_float4(v[0], v[1], v[2], v[3]);
        }
    }
}

extern "C" void kernel_launch(void* const* d_in, const int* in_sizes, int n_in,
                              void* d_out, int out_size, void* d_ws, size_t ws_size,
                              hipStream_t stream)
{
    const float* gt = (const float*)d_in[0];
    float* out = (float*)d_out;
    sapd_targets<<<dim3(86, 16), 256, 0, stream>>>(gt, out);
}